// Round 3
// baseline (4025.932 us; speedup 1.0000x reference)
//
#include <hip/hip_runtime.h>
#include <math.h>

// QLSTMHarmonic: persistent LSTM, 1 batch element/thread, 256 blk x 512 thr
// (B=131072 threads, all co-resident: __launch_bounds__(512,2) -> <=256 VGPR,
// 1 block/CU x 256 CUs). 131 global max-reduce phases via a double-buffered
// {tag,val} slot protocol in ws (zeroed by kinit). NO cooperative launch
// (not graph-capturable; round-0 evidence: node dropped from graph).
// Numerics: XLA-matched tanh/sigmoid (Eigen rational + logistic expander
// form), IEEE division wherever the reference divides, exact n/63, n/31 LUTs.

#define NBLK  256
#define NTHR  512
#define SEQL  64
#define HIDN  20
#define G4    80     // 4*HID gates

// XLA/Eigen f32 tanh rational approximation (matches XLA CPU+GPU lowering).
__device__ __forceinline__ float tanh_xla(float x){
  const float kClamp = 7.90531110763549805f;
  float xc = fminf(fmaxf(x, -kClamp), kClamp);
  float x2 = xc*xc;
  float p = fmaf(x2, -2.76076847742355e-16f, 2.00018790482477e-13f);
  p = fmaf(x2, p, -8.60467152213735e-11f);
  p = fmaf(x2, p,  5.12229709037114e-08f);
  p = fmaf(x2, p,  1.48572235717979e-05f);
  p = fmaf(x2, p,  6.37261928875436e-04f);
  p = fmaf(x2, p,  4.89352455891786e-03f);
  p = p * xc;
  float q = fmaf(x2, 1.19825839466702e-06f, 1.18534705686654e-04f);
  q = fmaf(x2, q, 2.26843463243900e-03f);
  q = fmaf(x2, q, 4.89352518554385e-03f);
  float y = p / q;                       // IEEE div, as XLA emits
  return (fabsf(x) < 4e-4f) ? x : y;     // XLA small-x passthrough
}

// Combined global max-reduce + barrier for one phase. All threads call;
// returns global max across all 256 blocks. tags/vals: 2 rows x NBLK each,
// row = phase&1, published tag = phase+1. A row is reused 2 phases later,
// strictly after every block has passed the intervening barrier, so all
// readers of the prior use are done (no ABA).
__device__ __forceinline__ float phase_max(float lmax, int phase,
                                           unsigned int* tags, unsigned int* vals,
                                           int blk, int tid, float* s_red, float* s_bc)
{
  #pragma unroll
  for (int off=32; off; off>>=1) lmax = fmaxf(lmax, __shfl_xor(lmax, off, 64));
  int wid = tid>>6, lane = tid&63;
  if (lane==0) s_red[wid] = lmax;
  __syncthreads();
  if (wid==0) {
    float bm = s_red[lane&7];                    // 8 waves/block
    bm = fmaxf(bm, __shfl_xor(bm,4,64));
    bm = fmaxf(bm, __shfl_xor(bm,2,64));
    bm = fmaxf(bm, __shfl_xor(bm,1,64));
    const int row = (phase&1)*NBLK;
    const unsigned int tag = (unsigned int)(phase+1);
    unsigned int* tp = tags + row;
    unsigned int* vp = vals + row;
    if (lane==0) {
      __hip_atomic_store(vp+blk, __float_as_uint(bm), __ATOMIC_RELAXED, __HIP_MEMORY_SCOPE_AGENT);
      __hip_atomic_store(tp+blk, tag, __ATOMIC_RELEASE, __HIP_MEMORY_SCOPE_AGENT);
    }
    for (;;) {
      unsigned int t0 = __hip_atomic_load(tp+lane,     __ATOMIC_ACQUIRE, __HIP_MEMORY_SCOPE_AGENT);
      unsigned int t1 = __hip_atomic_load(tp+lane+64,  __ATOMIC_ACQUIRE, __HIP_MEMORY_SCOPE_AGENT);
      unsigned int t2 = __hip_atomic_load(tp+lane+128, __ATOMIC_ACQUIRE, __HIP_MEMORY_SCOPE_AGENT);
      unsigned int t3 = __hip_atomic_load(tp+lane+192, __ATOMIC_ACQUIRE, __HIP_MEMORY_SCOPE_AGENT);
      if (__all(t0==tag && t1==tag && t2==tag && t3==tag)) break;
      __builtin_amdgcn_s_sleep(1);
    }
    unsigned int v0 = __hip_atomic_load(vp+lane,     __ATOMIC_RELAXED, __HIP_MEMORY_SCOPE_AGENT);
    unsigned int v1 = __hip_atomic_load(vp+lane+64,  __ATOMIC_RELAXED, __HIP_MEMORY_SCOPE_AGENT);
    unsigned int v2 = __hip_atomic_load(vp+lane+128, __ATOMIC_RELAXED, __HIP_MEMORY_SCOPE_AGENT);
    unsigned int v3 = __hip_atomic_load(vp+lane+192, __ATOMIC_RELAXED, __HIP_MEMORY_SCOPE_AGENT);
    unsigned int m = v0>v1?v0:v1; if (v2>m) m=v2; if (v3>m) m=v3;
    #pragma unroll
    for (int off=32; off; off>>=1) {
      unsigned int o = (unsigned int)__shfl_xor((int)m, off, 64);
      if (o>m) m=o;
    }
    if (lane==0) *s_bc = __uint_as_float(m);   // non-negative: uint cmp == float cmp
  }
  __syncthreads();
  return *s_bc;
}

__global__ void kinit(float* __restrict__ ws) {
  int i = threadIdx.x;
  for (; i < 1152; i += 256) ws[i] = 0.0f;     // xmax + scales + tags + vals
}

__global__ void kmaxabs_x(const float4* __restrict__ x4, int n4, int* __restrict__ xmax_bits) {
  float m = 0.f;
  int stride = gridDim.x*blockDim.x;
  for (int i = blockIdx.x*blockDim.x + threadIdx.x; i < n4; i += stride) {
    float4 v = x4[i];
    m = fmaxf(fmaxf(fabsf(v.x),fabsf(v.y)), fmaxf(fmaxf(fabsf(v.z),fabsf(v.w)), m));
  }
  #pragma unroll
  for (int off=32; off; off>>=1) m = fmaxf(m, __shfl_xor(m, off, 64));
  __shared__ float red[4];
  int wid = threadIdx.x>>6, lane = threadIdx.x&63;
  if (lane==0) red[wid]=m;
  __syncthreads();
  if (threadIdx.x==0) {
    float bm = fmaxf(fmaxf(red[0],red[1]), fmaxf(red[2],red[3]));
    atomicMax(xmax_bits, __float_as_int(bm));  // ws[0] zeroed by kinit; values >= 0
  }
}

__global__ void kscales(const float* __restrict__ wih, const float* __restrict__ whh,
                        const float* __restrict__ W1, const float* __restrict__ W2,
                        const float* __restrict__ W3, float* __restrict__ ws)
{
  int wid = threadIdx.x>>6, lane = threadIdx.x&63;
  const float* p; int n;
  if      (wid==0){p=wih;n=80;}   else if (wid==1){p=whh;n=1600;}
  else if (wid==2){p=W1;n=1280;}  else if (wid==3){p=W2;n=2048;}
  else            {p=W3;n=128;}
  float m=0.f;
  for (int i=lane;i<n;i+=64) m=fmaxf(m,fabsf(p[i]));
  #pragma unroll
  for (int off=32; off; off>>=1) m=fmaxf(m,__shfl_xor(m,off,64));
  if (lane==0) ws[9+wid]=fmaxf(m,1e-8f)/127.0f;
  if (threadIdx.x==0) {
    float xm = __int_as_float(((const int*)ws)[0]);
    ws[8]=fmaxf(xm,1e-8f)/127.0f;
  }
}

__global__ void __launch_bounds__(NTHR, 2)
kmain(const float* __restrict__ x, const float* __restrict__ w_ih,
      const float* __restrict__ w_hh, const float* __restrict__ bias,
      const float* __restrict__ W1, const float* __restrict__ b1,
      const float* __restrict__ W2, const float* __restrict__ b2,
      const float* __restrict__ W3, const float* __restrict__ b3,
      float* __restrict__ out, float* __restrict__ ws)
{
  __shared__ float s_whh[HIDN*G4];   // [k][j]
  __shared__ float s_wih[G4];
  __shared__ float s_b[G4];
  __shared__ float s_W1[HIDN*64];    // [k][j]
  __shared__ float s_b1v[64];
  __shared__ float s_W2[64*32];      // [k][j]
  __shared__ float s_b2v[32];
  __shared__ float s_W3[32*4];       // [k][j]
  __shared__ float s_b3v[4];
  __shared__ float s_t63[64];        // exact n/63
  __shared__ float s_t31[63];        // exact (n-31)/31
  __shared__ float s_red[8];
  __shared__ float s_bc;

  const int tid = threadIdx.x;
  const int blk = blockIdx.x;
  unsigned int* tags = (unsigned int*)(ws + 64);          // 2*NBLK uints
  unsigned int* vals = (unsigned int*)(ws + 64 + 2*NBLK); // 2*NBLK uints

  const float sx   = ws[8];
  const float swih = ws[9];
  const float swhh = ws[10];
  const float sw1  = ws[11];
  const float sw2  = ws[12];
  const float sw3  = ws[13];

  // stage + fake-quantize weights into LDS ([k][j] layout, float4 j-reads).
  // IEEE division: upstream (weights, exact max) is bit-exact -> quantized
  // weights match the reference bit-for-bit.
  for (int i = tid; i < G4; i += NTHR) {
    s_wih[i] = fminf(fmaxf(rintf(w_ih[i]/swih), -127.f), 127.f)*swih;
    s_b[i]   = bias[i];
  }
  for (int i = tid; i < HIDN*G4; i += NTHR) {
    int j = i/HIDN, k = i - j*HIDN;           // src w_hh[j][k]
    s_whh[k*G4+j] = fminf(fmaxf(rintf(w_hh[i]/swhh), -127.f), 127.f)*swhh;
  }
  for (int i = tid; i < 64*HIDN; i += NTHR) {
    int j = i/HIDN, k = i - j*HIDN;           // src W1[j][k]
    s_W1[k*64+j] = fminf(fmaxf(rintf(W1[i]/sw1), -127.f), 127.f)*sw1;
  }
  for (int i = tid; i < 32*64; i += NTHR) {
    int j = i>>6, k = i&63;                   // src W2[j][k]
    s_W2[k*32+j] = fminf(fmaxf(rintf(W2[i]/sw2), -127.f), 127.f)*sw2;
  }
  for (int i = tid; i < 4*32; i += NTHR) {
    int j = i>>5, k = i&31;                   // src W3[j][k]
    s_W3[k*4+j] = fminf(fmaxf(rintf(W3[i]/sw3), -127.f), 127.f)*sw3;
  }
  if (tid < 64) s_b1v[tid] = b1[tid];
  if (tid < 32) s_b2v[tid] = b2[tid];
  if (tid < 4)  s_b3v[tid] = b3[tid];
  if (tid < 64) s_t63[tid] = (float)tid / 63.0f;          // exact quotients
  if (tid < 63) s_t31[tid] = (float)(tid-31) / 31.0f;
  __syncthreads();

  const long bI = (long)blk*NTHR + tid;
  const float* xrow = x + bI*SEQL;

  float h[HIDN], c[HIDN];
  #pragma unroll
  for (int k=0;k<HIDN;++k){ h[k]=0.f; c[k]=0.f; }

  float4 x4v;
  #pragma unroll 1
  for (int t=0; t<SEQL; ++t) {
    if ((t&3)==0) x4v = *(const float4*)(xrow + t);
    float xv = (t&3)==1 ? x4v.y : ((t&3)==2 ? x4v.z : ((t&3)==3 ? x4v.w : x4v.x));
    float xq = fminf(fmaxf(rintf(xv/sx), -127.f), 127.f)*sx;  // io_quant 8b, IEEE div

    // hw = h @ w_hh^T, k-ordered fma from 0 (canonical dot order)
    float hw[G4];
    #pragma unroll
    for (int j=0;j<G4;++j) hw[j]=0.f;
    #pragma unroll
    for (int k=0;k<HIDN;++k) {
      float hk = h[k];
      #pragma unroll
      for (int j=0;j<G4;j+=4) {
        float4 w = *(const float4*)&s_whh[k*G4+j];
        hw[j]   = fmaf(hk, w.x, hw[j]);
        hw[j+1] = fmaf(hk, w.y, hw[j+1]);
        hw[j+2] = fmaf(hk, w.z, hw[j+2]);
        hw[j+3] = fmaf(hk, w.w, hw[j+3]);
      }
    }
    // gates = (x@wihT + hw) + b, left-assoc, no contraction
    float lm = 0.f;
    #pragma unroll
    for (int j=0;j<G4;++j) {
      float g = __fadd_rn(__fadd_rn(__fmul_rn(xq, s_wih[j]), hw[j]), s_b[j]);
      hw[j] = g;
      lm = fmaxf(lm, fabsf(g));
    }
    float gm = phase_max(lm, 2*t, tags, vals, blk, tid, s_red, &s_bc);
    float s1 = fmaxf(gm, 1e-8f)/31.0f;        // gate_acc quant, 6b signed
    #pragma unroll
    for (int j=0;j<G4;++j) {
      float n = fminf(fmaxf(rintf(hw[j]/s1), -31.f), 31.f);   // IEEE div
      hw[j] = __fmul_rn(n, s1);
    }

    float og[HIDN];
    float lm2 = 0.f;
    #pragma unroll
    for (int k=0;k<HIDN;++k) {
      // sigmoid = 0.5 + 0.5*tanh(0.5x) (XLA logistic expander), 6b quant via LUT
      float ti = tanh_xla(0.5f*hw[k   ]);
      float tf = tanh_xla(0.5f*hw[20+k]);
      float to = tanh_xla(0.5f*hw[60+k]);
      int ni = (int)rintf(fmaf(0.5f, ti, 0.5f)*63.0f);
      int nf = (int)rintf(fmaf(0.5f, tf, 0.5f)*63.0f);
      int no = (int)rintf(fmaf(0.5f, to, 0.5f)*63.0f);
      float iv = s_t63[min(max(ni,0),63)];
      float fv = s_t63[min(max(nf,0),63)];
      og[k]    = s_t63[min(max(no,0),63)];
      float tg = tanh_xla(hw[40+k]);
      int ng = (int)rintf(tg*31.0f);
      float gv = s_t31[min(max(ng+31,0),62)];
      // c_new = (f*c) + (i*g), unfused
      float pc = __fadd_rn(__fmul_rn(fv, c[k]), __fmul_rn(iv, gv));
      c[k] = pc;
      lm2 = fmaxf(lm2, fabsf(pc));
    }
    float gm2 = phase_max(lm2, 2*t+1, tags, vals, blk, tid, s_red, &s_bc);
    float s2 = fmaxf(gm2, 1e-8f)/31.0f;       // cell_state quant, 6b signed
    #pragma unroll
    for (int k=0;k<HIDN;++k) {
      float n  = fminf(fmaxf(rintf(c[k]/s2), -31.f), 31.f);   // IEEE div
      float cn = __fmul_rn(n, s2);
      c[k] = cn;
      float tc = tanh_xla(cn);
      int nc = (int)rintf(tc*31.0f);
      h[k] = __fmul_rn(og[k], s_t31[min(max(nc+31,0),62)]);
    }
  }

  // ---- MLP head ----
  float lm3 = 0.f;
  float a0[HIDN];
  #pragma unroll
  for (int k=0;k<HIDN;++k){ float r = fmaxf(h[k],0.f); a0[k]=r; lm3=fmaxf(lm3,r); }
  float gm3 = phase_max(lm3, 128, tags, vals, blk, tid, s_red, &s_bc);
  float s3 = fmaxf(gm3,1e-8f)/63.0f;          // unsigned 6b
  #pragma unroll
  for (int k=0;k<HIDN;++k)
    a0[k] = __fmul_rn(fminf(fmaxf(rintf(a0[k]/s3),0.f),63.f), s3);

  float o1[64];
  #pragma unroll
  for (int j=0;j<64;++j) o1[j] = 0.f;
  #pragma unroll
  for (int k=0;k<HIDN;++k) {
    float ak = a0[k];
    #pragma unroll
    for (int j=0;j<64;j+=4) {
      float4 w = *(const float4*)&s_W1[k*64+j];
      o1[j]   = fmaf(ak,w.x,o1[j]);
      o1[j+1] = fmaf(ak,w.y,o1[j+1]);
      o1[j+2] = fmaf(ak,w.z,o1[j+2]);
      o1[j+3] = fmaf(ak,w.w,o1[j+3]);
    }
  }
  float lm4 = 0.f;
  #pragma unroll
  for (int j=0;j<64;++j){ o1[j]=fmaxf(__fadd_rn(o1[j],s_b1v[j]),0.f); lm4=fmaxf(lm4,o1[j]); }
  float gm4 = phase_max(lm4, 129, tags, vals, blk, tid, s_red, &s_bc);
  float s4 = fmaxf(gm4,1e-8f)/63.0f;
  #pragma unroll
  for (int j=0;j<64;++j)
    o1[j] = __fmul_rn(fminf(fmaxf(rintf(o1[j]/s4),0.f),63.f), s4);

  float o2[32];
  #pragma unroll
  for (int j=0;j<32;++j) o2[j] = 0.f;
  #pragma unroll
  for (int k=0;k<64;++k) {
    float ak = o1[k];
    #pragma unroll
    for (int j=0;j<32;j+=4) {
      float4 w = *(const float4*)&s_W2[k*32+j];
      o2[j]   = fmaf(ak,w.x,o2[j]);
      o2[j+1] = fmaf(ak,w.y,o2[j+1]);
      o2[j+2] = fmaf(ak,w.z,o2[j+2]);
      o2[j+3] = fmaf(ak,w.w,o2[j+3]);
    }
  }
  float lm5=0.f;
  #pragma unroll
  for (int j=0;j<32;++j){ o2[j]=fmaxf(__fadd_rn(o2[j],s_b2v[j]),0.f); lm5=fmaxf(lm5,o2[j]); }
  float gm5 = phase_max(lm5, 130, tags, vals, blk, tid, s_red, &s_bc);
  float s5 = fmaxf(gm5,1e-8f)/63.0f;
  #pragma unroll
  for (int j=0;j<32;++j)
    o2[j] = __fmul_rn(fminf(fmaxf(rintf(o2[j]/s5),0.f),63.f), s5);

  float o3[4] = {0.f,0.f,0.f,0.f};
  #pragma unroll
  for (int k=0;k<32;++k) {
    float ak = o2[k];
    float4 w = *(const float4*)&s_W3[k*4];
    o3[0]=fmaf(ak,w.x,o3[0]); o3[1]=fmaf(ak,w.y,o3[1]);
    o3[2]=fmaf(ak,w.z,o3[2]); o3[3]=fmaf(ak,w.w,o3[3]);
  }
  float4 res;
  res.x = fmaxf(__fadd_rn(o3[0],s_b3v[0]),0.f);
  res.y = fmaxf(__fadd_rn(o3[1],s_b3v[1]),0.f);
  res.z = fmaxf(__fadd_rn(o3[2],s_b3v[2]),0.f);
  res.w = fmaxf(__fadd_rn(o3[3],s_b3v[3]),0.f);
  ((float4*)out)[bI] = res;
}

extern "C" void kernel_launch(void* const* d_in, const int* in_sizes, int n_in,
                              void* d_out, int out_size, void* d_ws, size_t ws_size,
                              hipStream_t stream) {
  const float* x    = (const float*)d_in[0];
  const float* w_ih = (const float*)d_in[1];
  const float* w_hh = (const float*)d_in[2];
  const float* b    = (const float*)d_in[3];
  const float* W1   = (const float*)d_in[4];
  const float* b1   = (const float*)d_in[5];
  const float* W2   = (const float*)d_in[6];
  const float* b2   = (const float*)d_in[7];
  const float* W3   = (const float*)d_in[8];
  const float* b3   = (const float*)d_in[9];
  float* out = (float*)d_out;
  float* ws  = (float*)d_ws;

  int n4 = in_sizes[0]/4;
  kinit<<<1,256,0,stream>>>(ws);
  kmaxabs_x<<<1024,256,0,stream>>>((const float4*)x, n4, (int*)ws);
  kscales<<<1,320,0,stream>>>(w_ih,w_hh,W1,W2,W3,ws);
  // Plain launch (NOT cooperative: not graph-capturable). Co-residency is
  // structural: 256 blocks, 1 block/CU x 256 CUs at __launch_bounds__(512,2).
  kmain<<<dim3(NBLK), dim3(NTHR), 0, stream>>>(x,w_ih,w_hh,b,W1,b1,W2,b2,W3,b3,out,ws);
}

// Round 4
// 3300.443 us; speedup vs baseline: 1.2198x; 1.2198x over previous
//
#include <hip/hip_runtime.h>
#include <math.h>

// QLSTMHarmonic: persistent LSTM, 1 batch element/thread, 256 blk x 512 thr
// (B=131072 threads, all co-resident: __launch_bounds__(512,2) -> <=256 VGPR,
// 1 block/CU x 256 CUs). 131 global max-reduce phases via double-buffered
// {tag,val} slot protocol in ws. Bit-exact numerics (round-3: absmax 0.0):
// XLA/Eigen tanh, logistic-expander sigmoid, ties-even rounding.
// Round-4 changes (both bit-exactness-preserving):
//  1) Per-phase activation LUTs: quantized gates take only 63 distinct values
//     n*s1 (n in [-31,31]) -> 126 threads build sigmoid/tanh LUTs in LDS with
//     the exact same instruction sequence; everyone else does ds_read lookups.
//     Deletes ~100 tanh_xla calls (~2600 VALU instr) per thread-step.
//  2) Guarded quant: rintf(x/s) via x*rcp(s) fast path + exact-residual
//     boundary check (fallback to IEEE div only within tol of a rounding
//     boundary; tol >> fast-path error bound, so result is provably
//     identical to rintf(RN(x/s))). Deletes ~100 IEEE divs per thread-step.

#define NBLK  256
#define NTHR  512
#define SEQL  64
#define HIDN  20
#define G4    80     // 4*HID gates

// XLA/Eigen f32 tanh rational approximation (matches XLA lowering; validated
// bit-exact round 3).
__device__ __forceinline__ float tanh_xla(float x){
  const float kClamp = 7.90531110763549805f;
  float xc = fminf(fmaxf(x, -kClamp), kClamp);
  float x2 = xc*xc;
  float p = fmaf(x2, -2.76076847742355e-16f, 2.00018790482477e-13f);
  p = fmaf(x2, p, -8.60467152213735e-11f);
  p = fmaf(x2, p,  5.12229709037114e-08f);
  p = fmaf(x2, p,  1.48572235717979e-05f);
  p = fmaf(x2, p,  6.37261928875436e-04f);
  p = fmaf(x2, p,  4.89352455891786e-03f);
  p = p * xc;
  float q = fmaf(x2, 1.19825839466702e-06f, 1.18534705686654e-04f);
  q = fmaf(x2, q, 2.26843463243900e-03f);
  q = fmaf(x2, q, 4.89352518554385e-03f);
  float y = p / q;                       // IEEE div, as XLA emits
  return (fabsf(x) < 4e-4f) ? x : y;     // XLA small-x passthrough
}

// n = rintf(RN(x/s)) without a division in the common case.
// Fast path: n0 = rintf(x*inv_s) with inv_s = v_rcp(s) (<=1 ulp). n0 can only
// disagree with the exact result when x/s is within ~qmax*2.5ulp of a
// half-integer boundary; residual e = fma(-n0,s,x) measures that distance with
// single rounding. If within tol of the boundary, redo with the exact IEEE div
// (also covers rintf's double-rounding/ties-even edge). tol chosen per qmax:
// qmax*1.8e-7 << tol, and tol small enough that fallback is ~1e-4 rare.
__device__ __forceinline__ float qround(float x, float s, float inv_s, float tol){
  float n = rintf(__fmul_rn(x, inv_s));
  float e = fmaf(-n, s, x);
  if (__builtin_expect(fabsf(fabsf(e) - 0.5f*s) <= tol*s, 0))
    n = rintf(x / s);
  return n;
}

// Combined global max-reduce + barrier for one phase. All threads call;
// returns global max across all 256 blocks. tags/vals: 2 rows x NBLK each,
// row = phase&1, published tag = phase+1. A row is reused 2 phases later,
// strictly after the intervening barrier, so no ABA.
__device__ __forceinline__ float phase_max(float lmax, int phase,
                                           unsigned int* tags, unsigned int* vals,
                                           int blk, int tid, float* s_red, float* s_bc)
{
  #pragma unroll
  for (int off=32; off; off>>=1) lmax = fmaxf(lmax, __shfl_xor(lmax, off, 64));
  int wid = tid>>6, lane = tid&63;
  if (lane==0) s_red[wid] = lmax;
  __syncthreads();
  if (wid==0) {
    float bm = s_red[lane&7];                    // 8 waves/block
    bm = fmaxf(bm, __shfl_xor(bm,4,64));
    bm = fmaxf(bm, __shfl_xor(bm,2,64));
    bm = fmaxf(bm, __shfl_xor(bm,1,64));
    const int row = (phase&1)*NBLK;
    const unsigned int tag = (unsigned int)(phase+1);
    unsigned int* tp = tags + row;
    unsigned int* vp = vals + row;
    if (lane==0) {
      __hip_atomic_store(vp+blk, __float_as_uint(bm), __ATOMIC_RELAXED, __HIP_MEMORY_SCOPE_AGENT);
      __hip_atomic_store(tp+blk, tag, __ATOMIC_RELEASE, __HIP_MEMORY_SCOPE_AGENT);
    }
    for (;;) {
      unsigned int t0 = __hip_atomic_load(tp+lane,     __ATOMIC_ACQUIRE, __HIP_MEMORY_SCOPE_AGENT);
      unsigned int t1 = __hip_atomic_load(tp+lane+64,  __ATOMIC_ACQUIRE, __HIP_MEMORY_SCOPE_AGENT);
      unsigned int t2 = __hip_atomic_load(tp+lane+128, __ATOMIC_ACQUIRE, __HIP_MEMORY_SCOPE_AGENT);
      unsigned int t3 = __hip_atomic_load(tp+lane+192, __ATOMIC_ACQUIRE, __HIP_MEMORY_SCOPE_AGENT);
      if (__all(t0==tag && t1==tag && t2==tag && t3==tag)) break;
      __builtin_amdgcn_s_sleep(1);
    }
    unsigned int v0 = __hip_atomic_load(vp+lane,     __ATOMIC_RELAXED, __HIP_MEMORY_SCOPE_AGENT);
    unsigned int v1 = __hip_atomic_load(vp+lane+64,  __ATOMIC_RELAXED, __HIP_MEMORY_SCOPE_AGENT);
    unsigned int v2 = __hip_atomic_load(vp+lane+128, __ATOMIC_RELAXED, __HIP_MEMORY_SCOPE_AGENT);
    unsigned int v3 = __hip_atomic_load(vp+lane+192, __ATOMIC_RELAXED, __HIP_MEMORY_SCOPE_AGENT);
    unsigned int m = v0>v1?v0:v1; if (v2>m) m=v2; if (v3>m) m=v3;
    #pragma unroll
    for (int off=32; off; off>>=1) {
      unsigned int o = (unsigned int)__shfl_xor((int)m, off, 64);
      if (o>m) m=o;
    }
    if (lane==0) *s_bc = __uint_as_float(m);   // non-negative: uint cmp == float cmp
  }
  __syncthreads();
  return *s_bc;
}

__global__ void kinit(float* __restrict__ ws) {
  int i = threadIdx.x;
  for (; i < 1152; i += 256) ws[i] = 0.0f;     // xmax + scales + tags + vals
}

__global__ void kmaxabs_x(const float4* __restrict__ x4, int n4, int* __restrict__ xmax_bits) {
  float m = 0.f;
  int stride = gridDim.x*blockDim.x;
  for (int i = blockIdx.x*blockDim.x + threadIdx.x; i < n4; i += stride) {
    float4 v = x4[i];
    m = fmaxf(fmaxf(fabsf(v.x),fabsf(v.y)), fmaxf(fmaxf(fabsf(v.z),fabsf(v.w)), m));
  }
  #pragma unroll
  for (int off=32; off; off>>=1) m = fmaxf(m, __shfl_xor(m, off, 64));
  __shared__ float red[4];
  int wid = threadIdx.x>>6, lane = threadIdx.x&63;
  if (lane==0) red[wid]=m;
  __syncthreads();
  if (threadIdx.x==0) {
    float bm = fmaxf(fmaxf(red[0],red[1]), fmaxf(red[2],red[3]));
    atomicMax(xmax_bits, __float_as_int(bm));  // ws[0] zeroed by kinit; values >= 0
  }
}

__global__ void kscales(const float* __restrict__ wih, const float* __restrict__ whh,
                        const float* __restrict__ W1, const float* __restrict__ W2,
                        const float* __restrict__ W3, float* __restrict__ ws)
{
  int wid = threadIdx.x>>6, lane = threadIdx.x&63;
  const float* p; int n;
  if      (wid==0){p=wih;n=80;}   else if (wid==1){p=whh;n=1600;}
  else if (wid==2){p=W1;n=1280;}  else if (wid==3){p=W2;n=2048;}
  else            {p=W3;n=128;}
  float m=0.f;
  for (int i=lane;i<n;i+=64) m=fmaxf(m,fabsf(p[i]));
  #pragma unroll
  for (int off=32; off; off>>=1) m=fmaxf(m,__shfl_xor(m,off,64));
  if (lane==0) ws[9+wid]=fmaxf(m,1e-8f)/127.0f;
  if (threadIdx.x==0) {
    float xm = __int_as_float(((const int*)ws)[0]);
    ws[8]=fmaxf(xm,1e-8f)/127.0f;
  }
}

__global__ void __launch_bounds__(NTHR, 2)
kmain(const float* __restrict__ x, const float* __restrict__ w_ih,
      const float* __restrict__ w_hh, const float* __restrict__ bias,
      const float* __restrict__ W1, const float* __restrict__ b1,
      const float* __restrict__ W2, const float* __restrict__ b2,
      const float* __restrict__ W3, const float* __restrict__ b3,
      float* __restrict__ out, float* __restrict__ ws)
{
  __shared__ float s_whh[HIDN*G4];   // [k][j]
  __shared__ float s_wih[G4];
  __shared__ float s_b[G4];
  __shared__ float s_W1[HIDN*64];    // [k][j]
  __shared__ float s_b1v[64];
  __shared__ float s_W2[64*32];      // [k][j]
  __shared__ float s_b2v[32];
  __shared__ float s_W3[32*4];       // [k][j]
  __shared__ float s_b3v[4];
  __shared__ float s_lutsig[63];     // per-gate-phase: quantized sigmoid of n*s1
  __shared__ float s_luttg[63];      // per-gate-phase: quantized tanh of n*s1
  __shared__ float s_luttc[63];      // per-cell-phase: quantized tanh of m*s2
  __shared__ float s_red[8];
  __shared__ float s_bc;

  const int tid = threadIdx.x;
  const int blk = blockIdx.x;
  unsigned int* tags = (unsigned int*)(ws + 64);          // 2*NBLK uints
  unsigned int* vals = (unsigned int*)(ws + 64 + 2*NBLK); // 2*NBLK uints

  const float sx   = ws[8];
  const float swih = ws[9];
  const float swhh = ws[10];
  const float sw1  = ws[11];
  const float sw2  = ws[12];
  const float sw3  = ws[13];

  // stage + fake-quantize weights into LDS ([k][j] layout, float4 j-reads).
  // One-time cost: IEEE div keeps this bit-exact vs reference.
  for (int i = tid; i < G4; i += NTHR) {
    s_wih[i] = fminf(fmaxf(rintf(w_ih[i]/swih), -127.f), 127.f)*swih;
    s_b[i]   = bias[i];
  }
  for (int i = tid; i < HIDN*G4; i += NTHR) {
    int j = i/HIDN, k = i - j*HIDN;           // src w_hh[j][k]
    s_whh[k*G4+j] = fminf(fmaxf(rintf(w_hh[i]/swhh), -127.f), 127.f)*swhh;
  }
  for (int i = tid; i < 64*HIDN; i += NTHR) {
    int j = i/HIDN, k = i - j*HIDN;           // src W1[j][k]
    s_W1[k*64+j] = fminf(fmaxf(rintf(W1[i]/sw1), -127.f), 127.f)*sw1;
  }
  for (int i = tid; i < 32*64; i += NTHR) {
    int j = i>>6, k = i&63;                   // src W2[j][k]
    s_W2[k*32+j] = fminf(fmaxf(rintf(W2[i]/sw2), -127.f), 127.f)*sw2;
  }
  for (int i = tid; i < 4*32; i += NTHR) {
    int j = i>>5, k = i&31;                   // src W3[j][k]
    s_W3[k*4+j] = fminf(fmaxf(rintf(W3[i]/sw3), -127.f), 127.f)*sw3;
  }
  if (tid < 64) s_b1v[tid] = b1[tid];
  if (tid < 32) s_b2v[tid] = b2[tid];
  if (tid < 4)  s_b3v[tid] = b3[tid];
  __syncthreads();

  const long bI = (long)blk*NTHR + tid;
  const float* xrow = x + bI*SEQL;
  const float inv_sx = __builtin_amdgcn_rcpf(sx);

  float h[HIDN], c[HIDN];
  #pragma unroll
  for (int k=0;k<HIDN;++k){ h[k]=0.f; c[k]=0.f; }

  float4 x4v;
  #pragma unroll 1
  for (int t=0; t<SEQL; ++t) {
    if ((t&3)==0) x4v = *(const float4*)(xrow + t);
    float xv = (t&3)==1 ? x4v.y : ((t&3)==2 ? x4v.z : ((t&3)==3 ? x4v.w : x4v.x));
    float xq = __fmul_rn(fminf(fmaxf(qround(xv, sx, inv_sx, 1e-4f), -127.f), 127.f), sx);

    // hw = h @ w_hh^T, k-ordered fma from 0 (canonical dot order)
    float hw[G4];
    #pragma unroll
    for (int j=0;j<G4;++j) hw[j]=0.f;
    #pragma unroll
    for (int k=0;k<HIDN;++k) {
      float hk = h[k];
      #pragma unroll
      for (int j=0;j<G4;j+=4) {
        float4 w = *(const float4*)&s_whh[k*G4+j];
        hw[j]   = fmaf(hk, w.x, hw[j]);
        hw[j+1] = fmaf(hk, w.y, hw[j+1]);
        hw[j+2] = fmaf(hk, w.z, hw[j+2]);
        hw[j+3] = fmaf(hk, w.w, hw[j+3]);
      }
    }
    // gates = (x@wihT + hw) + b, left-assoc, no contraction
    float lm = 0.f;
    #pragma unroll
    for (int j=0;j<G4;++j) {
      float g = __fadd_rn(__fadd_rn(__fmul_rn(xq, s_wih[j]), hw[j]), s_b[j]);
      hw[j] = g;
      lm = fmaxf(lm, fabsf(g));
    }
    float gm = phase_max(lm, 2*t, tags, vals, blk, tid, s_red, &s_bc);
    float s1 = fmaxf(gm, 1e-8f)/31.0f;        // gate_acc scale (uniform)
    float inv1 = __builtin_amdgcn_rcpf(s1);

    // Build activation LUTs for the 63 possible quantized-gate values.
    // Entry n: exact same instruction sequence as the former per-thread path
    // on input RN(n*s1) -> bit-identical results.
    if (tid < 63) {
      float q  = __fmul_rn((float)(tid-31), s1);
      float ti = tanh_xla(0.5f*q);
      int ni = (int)rintf(fmaf(0.5f, ti, 0.5f)*63.0f);
      ni = min(max(ni,0),63);
      s_lutsig[tid] = (float)ni/63.0f;
    } else if (tid >= 64 && tid < 127) {
      int n = tid - 64 - 31;
      float q  = __fmul_rn((float)n, s1);
      float tg = tanh_xla(q);
      int ng = (int)rintf(tg*31.0f);
      ng = min(max(ng,-31),31);
      s_luttg[tid-64] = (float)ng/31.0f;
    }
    __syncthreads();

    float og[HIDN];
    float lm2 = 0.f;
    #pragma unroll
    for (int k=0;k<HIDN;++k) {
      int ii = min(max((int)qround(hw[k   ], s1, inv1, 2e-5f),-31),31)+31;
      int fi = min(max((int)qround(hw[20+k], s1, inv1, 2e-5f),-31),31)+31;
      int gi = min(max((int)qround(hw[40+k], s1, inv1, 2e-5f),-31),31)+31;
      int oi = min(max((int)qround(hw[60+k], s1, inv1, 2e-5f),-31),31)+31;
      float iv = s_lutsig[ii];
      float fv = s_lutsig[fi];
      float gv = s_luttg[gi];
      og[k]    = s_lutsig[oi];
      // c_new = (f*c) + (i*g), unfused
      float pc = __fadd_rn(__fmul_rn(fv, c[k]), __fmul_rn(iv, gv));
      c[k] = pc;
      lm2 = fmaxf(lm2, fabsf(pc));
    }
    float gm2 = phase_max(lm2, 2*t+1, tags, vals, blk, tid, s_red, &s_bc);
    float s2 = fmaxf(gm2, 1e-8f)/31.0f;       // cell_state scale (uniform)
    float inv2 = __builtin_amdgcn_rcpf(s2);
    if (tid < 63) {
      float q  = __fmul_rn((float)(tid-31), s2);
      float tc = tanh_xla(q);
      int nc = (int)rintf(tc*31.0f);
      nc = min(max(nc,-31),31);
      s_luttc[tid] = (float)nc/31.0f;
    }
    __syncthreads();
    #pragma unroll
    for (int k=0;k<HIDN;++k) {
      int m = min(max((int)qround(c[k], s2, inv2, 2e-5f),-31),31);
      float cn = __fmul_rn((float)m, s2);
      c[k] = cn;
      h[k] = __fmul_rn(og[k], s_luttc[m+31]);
    }
  }

  // ---- MLP head ----
  float lm3 = 0.f;
  float a0[HIDN];
  #pragma unroll
  for (int k=0;k<HIDN;++k){ float r = fmaxf(h[k],0.f); a0[k]=r; lm3=fmaxf(lm3,r); }
  float gm3 = phase_max(lm3, 128, tags, vals, blk, tid, s_red, &s_bc);
  float s3 = fmaxf(gm3,1e-8f)/63.0f;          // unsigned 6b
  float inv3 = __builtin_amdgcn_rcpf(s3);
  #pragma unroll
  for (int k=0;k<HIDN;++k)
    a0[k] = __fmul_rn(fminf(fmaxf(qround(a0[k], s3, inv3, 4e-5f),0.f),63.f), s3);

  float o1[64];
  #pragma unroll
  for (int j=0;j<64;++j) o1[j] = 0.f;
  #pragma unroll
  for (int k=0;k<HIDN;++k) {
    float ak = a0[k];
    #pragma unroll
    for (int j=0;j<64;j+=4) {
      float4 w = *(const float4*)&s_W1[k*64+j];
      o1[j]   = fmaf(ak,w.x,o1[j]);
      o1[j+1] = fmaf(ak,w.y,o1[j+1]);
      o1[j+2] = fmaf(ak,w.z,o1[j+2]);
      o1[j+3] = fmaf(ak,w.w,o1[j+3]);
    }
  }
  float lm4 = 0.f;
  #pragma unroll
  for (int j=0;j<64;++j){ o1[j]=fmaxf(__fadd_rn(o1[j],s_b1v[j]),0.f); lm4=fmaxf(lm4,o1[j]); }
  float gm4 = phase_max(lm4, 129, tags, vals, blk, tid, s_red, &s_bc);
  float s4 = fmaxf(gm4,1e-8f)/63.0f;
  float inv4 = __builtin_amdgcn_rcpf(s4);
  #pragma unroll
  for (int j=0;j<64;++j)
    o1[j] = __fmul_rn(fminf(fmaxf(qround(o1[j], s4, inv4, 4e-5f),0.f),63.f), s4);

  float o2[32];
  #pragma unroll
  for (int j=0;j<32;++j) o2[j] = 0.f;
  #pragma unroll
  for (int k=0;k<64;++k) {
    float ak = o1[k];
    #pragma unroll
    for (int j=0;j<32;j+=4) {
      float4 w = *(const float4*)&s_W2[k*32+j];
      o2[j]   = fmaf(ak,w.x,o2[j]);
      o2[j+1] = fmaf(ak,w.y,o2[j+1]);
      o2[j+2] = fmaf(ak,w.z,o2[j+2]);
      o2[j+3] = fmaf(ak,w.w,o2[j+3]);
    }
  }
  float lm5=0.f;
  #pragma unroll
  for (int j=0;j<32;++j){ o2[j]=fmaxf(__fadd_rn(o2[j],s_b2v[j]),0.f); lm5=fmaxf(lm5,o2[j]); }
  float gm5 = phase_max(lm5, 130, tags, vals, blk, tid, s_red, &s_bc);
  float s5 = fmaxf(gm5,1e-8f)/63.0f;
  float inv5 = __builtin_amdgcn_rcpf(s5);
  #pragma unroll
  for (int j=0;j<32;++j)
    o2[j] = __fmul_rn(fminf(fmaxf(qround(o2[j], s5, inv5, 4e-5f),0.f),63.f), s5);

  float o3[4] = {0.f,0.f,0.f,0.f};
  #pragma unroll
  for (int k=0;k<32;++k) {
    float ak = o2[k];
    float4 w = *(const float4*)&s_W3[k*4];
    o3[0]=fmaf(ak,w.x,o3[0]); o3[1]=fmaf(ak,w.y,o3[1]);
    o3[2]=fmaf(ak,w.z,o3[2]); o3[3]=fmaf(ak,w.w,o3[3]);
  }
  float4 res;
  res.x = fmaxf(__fadd_rn(o3[0],s_b3v[0]),0.f);
  res.y = fmaxf(__fadd_rn(o3[1],s_b3v[1]),0.f);
  res.z = fmaxf(__fadd_rn(o3[2],s_b3v[2]),0.f);
  res.w = fmaxf(__fadd_rn(o3[3],s_b3v[3]),0.f);
  ((float4*)out)[bI] = res;
}

extern "C" void kernel_launch(void* const* d_in, const int* in_sizes, int n_in,
                              void* d_out, int out_size, void* d_ws, size_t ws_size,
                              hipStream_t stream) {
  const float* x    = (const float*)d_in[0];
  const float* w_ih = (const float*)d_in[1];
  const float* w_hh = (const float*)d_in[2];
  const float* b    = (const float*)d_in[3];
  const float* W1   = (const float*)d_in[4];
  const float* b1   = (const float*)d_in[5];
  const float* W2   = (const float*)d_in[6];
  const float* b2   = (const float*)d_in[7];
  const float* W3   = (const float*)d_in[8];
  const float* b3   = (const float*)d_in[9];
  float* out = (float*)d_out;
  float* ws  = (float*)d_ws;

  int n4 = in_sizes[0]/4;
  kinit<<<1,256,0,stream>>>(ws);
  kmaxabs_x<<<1024,256,0,stream>>>((const float4*)x, n4, (int*)ws);
  kscales<<<1,320,0,stream>>>(w_ih,w_hh,W1,W2,W3,ws);
  // Plain launch (NOT cooperative: not graph-capturable). Co-residency is
  // structural: 256 blocks, 1 block/CU x 256 CUs at __launch_bounds__(512,2).
  kmain<<<dim3(NBLK), dim3(NTHR), 0, stream>>>(x,w_ih,w_hh,b,W1,b1,W2,b2,W3,b3,out,ws);
}

// Round 6
// 1342.619 us; speedup vs baseline: 2.9986x; 2.4582x over previous
//
#include <hip/hip_runtime.h>
#include <math.h>

// QLSTMHarmonic: persistent LSTM, 1 batch element/thread, 256 blk x 512 thr
// (B=131072 threads, all co-resident; grid==CU count -> 1 block/CU).
// 131 serial global max-reduce phases. Round-5 change: barrier uses RELAXED
// 64-bit packed {tag,val} atomics (agent scope). Round-4's release/acquire
// protocol forced per-poll L2 writeback/invalidate on non-coherent-XCD
// gfx950 (~20us/phase, 80% of runtime). Single-word payload needs no
// ordering: atomicity of the 8B slot carries both tag and value.
// Numerics (bit-exact, absmax 0.0 rounds 3-4): XLA/Eigen tanh, logistic-
// expander sigmoid, per-phase activation LUTs, guarded-rcp quantization.

#define NBLK  256
#define NTHR  512
#define SEQL  64
#define HIDN  20
#define G4    80     // 4*HID gates

// XLA/Eigen f32 tanh rational approximation (bit-exact vs reference, r3/r4).
__device__ __forceinline__ float tanh_xla(float x){
  const float kClamp = 7.90531110763549805f;
  float xc = fminf(fmaxf(x, -kClamp), kClamp);
  float x2 = xc*xc;
  float p = fmaf(x2, -2.76076847742355e-16f, 2.00018790482477e-13f);
  p = fmaf(x2, p, -8.60467152213735e-11f);
  p = fmaf(x2, p,  5.12229709037114e-08f);
  p = fmaf(x2, p,  1.48572235717979e-05f);
  p = fmaf(x2, p,  6.37261928875436e-04f);
  p = fmaf(x2, p,  4.89352455891786e-03f);
  p = p * xc;
  float q = fmaf(x2, 1.19825839466702e-06f, 1.18534705686654e-04f);
  q = fmaf(x2, q, 2.26843463243900e-03f);
  q = fmaf(x2, q, 4.89352518554385e-03f);
  float y = p / q;                       // IEEE div, as XLA emits
  return (fabsf(x) < 4e-4f) ? x : y;     // XLA small-x passthrough
}

// n = rintf(RN(x/s)) without a division in the common case (validated
// bit-exact r4). Fallback to IEEE div only near a rounding boundary.
__device__ __forceinline__ float qround(float x, float s, float inv_s, float tol){
  float n = rintf(__fmul_rn(x, inv_s));
  float e = fmaf(-n, s, x);
  if (__builtin_expect(fabsf(fabsf(e) - 0.5f*s) <= tol*s, 0))
    n = rintf(x / s);
  return n;
}

// Combined global max-reduce + barrier for one phase. All threads call;
// returns global max across all 256 blocks. slots: 2 rows x NBLK x u64,
// row = phase&1, slot value = ((phase+1)<<32) | float_bits(block_max).
// RELAXED atomics only: the single 8B word is the entire cross-block
// payload, so no release/acquire (and no L2 wb/inv) is needed. Row reuse
// at phase p+2 is gated by barrier p+1 -> no poller of phase p is live.
__device__ __forceinline__ float phase_max(float lmax, int phase,
                                           unsigned long long* slots,
                                           int blk, int tid, float* s_red, float* s_bc)
{
  #pragma unroll
  for (int off=32; off; off>>=1) lmax = fmaxf(lmax, __shfl_xor(lmax, off, 64));
  int wid = tid>>6, lane = tid&63;
  if (lane==0) s_red[wid] = lmax;
  __syncthreads();
  if (wid==0) {
    float bm = s_red[lane&7];                    // 8 waves/block
    bm = fmaxf(bm, __shfl_xor(bm,4,64));
    bm = fmaxf(bm, __shfl_xor(bm,2,64));
    bm = fmaxf(bm, __shfl_xor(bm,1,64));
    unsigned long long* sp = slots + (size_t)(phase&1)*NBLK;
    const unsigned long long tagw = ((unsigned long long)(unsigned)(phase+1))<<32;
    if (lane==0)
      __hip_atomic_store(sp+blk, tagw | (unsigned long long)__float_as_uint(bm),
                         __ATOMIC_RELAXED, __HIP_MEMORY_SCOPE_AGENT);
    unsigned long long v0,v1,v2,v3;
    const unsigned int tag = (unsigned int)(phase+1);
    for (;;) {
      v0 = __hip_atomic_load(sp+lane,     __ATOMIC_RELAXED, __HIP_MEMORY_SCOPE_AGENT);
      v1 = __hip_atomic_load(sp+lane+64,  __ATOMIC_RELAXED, __HIP_MEMORY_SCOPE_AGENT);
      v2 = __hip_atomic_load(sp+lane+128, __ATOMIC_RELAXED, __HIP_MEMORY_SCOPE_AGENT);
      v3 = __hip_atomic_load(sp+lane+192, __ATOMIC_RELAXED, __HIP_MEMORY_SCOPE_AGENT);
      bool ok = ((unsigned)(v0>>32)==tag) && ((unsigned)(v1>>32)==tag) &&
                ((unsigned)(v2>>32)==tag) && ((unsigned)(v3>>32)==tag);
      if (__all(ok)) break;
      __builtin_amdgcn_s_sleep(1);
    }
    unsigned int m0 = (unsigned int)v0, m1 = (unsigned int)v1;
    unsigned int m2 = (unsigned int)v2, m3 = (unsigned int)v3;
    unsigned int m = m0>m1?m0:m1; if (m2>m) m=m2; if (m3>m) m=m3;
    #pragma unroll
    for (int off=32; off; off>>=1) {
      unsigned int o = (unsigned int)__shfl_xor((int)m, off, 64);
      if (o>m) m=o;
    }
    if (lane==0) *s_bc = __uint_as_float(m);   // non-negative: uint cmp == float cmp
  }
  __syncthreads();
  return *s_bc;
}

__global__ void kinit(float* __restrict__ ws) {
  int i = threadIdx.x;
  for (; i < 1152; i += 256) ws[i] = 0.0f;     // xmax + scales + 2x256 u64 slots
}

__global__ void kmaxabs_x(const float4* __restrict__ x4, int n4, int* __restrict__ xmax_bits) {
  float m = 0.f;
  int stride = gridDim.x*blockDim.x;
  for (int i = blockIdx.x*blockDim.x + threadIdx.x; i < n4; i += stride) {
    float4 v = x4[i];
    m = fmaxf(fmaxf(fabsf(v.x),fabsf(v.y)), fmaxf(fmaxf(fabsf(v.z),fabsf(v.w)), m));
  }
  #pragma unroll
  for (int off=32; off; off>>=1) m = fmaxf(m, __shfl_xor(m, off, 64));
  __shared__ float red[4];
  int wid = threadIdx.x>>6, lane = threadIdx.x&63;
  if (lane==0) red[wid]=m;
  __syncthreads();
  if (threadIdx.x==0) {
    float bm = fmaxf(fmaxf(red[0],red[1]), fmaxf(red[2],red[3]));
    atomicMax(xmax_bits, __float_as_int(bm));  // ws[0] zeroed by kinit; values >= 0
  }
}

__global__ void kscales(const float* __restrict__ wih, const float* __restrict__ whh,
                        const float* __restrict__ W1, const float* __restrict__ W2,
                        const float* __restrict__ W3, float* __restrict__ ws)
{
  int wid = threadIdx.x>>6, lane = threadIdx.x&63;
  const float* p; int n;
  if      (wid==0){p=wih;n=80;}   else if (wid==1){p=whh;n=1600;}
  else if (wid==2){p=W1;n=1280;}  else if (wid==3){p=W2;n=2048;}
  else            {p=W3;n=128;}
  float m=0.f;
  for (int i=lane;i<n;i+=64) m=fmaxf(m,fabsf(p[i]));
  #pragma unroll
  for (int off=32; off; off>>=1) m=fmaxf(m,__shfl_xor(m,off,64));
  if (lane==0) ws[9+wid]=fmaxf(m,1e-8f)/127.0f;
  if (threadIdx.x==0) {
    float xm = __int_as_float(((const int*)ws)[0]);
    ws[8]=fmaxf(xm,1e-8f)/127.0f;
  }
}

__global__ void __launch_bounds__(NTHR, 2)
kmain(const float* __restrict__ x, const float* __restrict__ w_ih,
      const float* __restrict__ w_hh, const float* __restrict__ bias,
      const float* __restrict__ W1, const float* __restrict__ b1,
      const float* __restrict__ W2, const float* __restrict__ b2,
      const float* __restrict__ W3, const float* __restrict__ b3,
      float* __restrict__ out, float* __restrict__ ws)
{
  __shared__ float s_whh[HIDN*G4];   // [k][j]
  __shared__ float s_wih[G4];
  __shared__ float s_b[G4];
  __shared__ float s_W1[HIDN*64];    // [k][j]
  __shared__ float s_b1v[64];
  __shared__ float s_W2[64*32];      // [k][j]
  __shared__ float s_b2v[32];
  __shared__ float s_W3[32*4];       // [k][j]
  __shared__ float s_b3v[4];
  __shared__ float s_lutsig[63];     // per-gate-phase: quantized sigmoid of n*s1
  __shared__ float s_luttg[63];      // per-gate-phase: quantized tanh of n*s1
  __shared__ float s_luttc[63];      // per-cell-phase: quantized tanh of m*s2
  __shared__ float s_red[8];
  __shared__ float s_bc;

  const int tid = threadIdx.x;
  const int blk = blockIdx.x;
  unsigned long long* slots = (unsigned long long*)(ws + 64);  // 2*NBLK u64

  const float sx   = ws[8];
  const float swih = ws[9];
  const float swhh = ws[10];
  const float sw1  = ws[11];
  const float sw2  = ws[12];
  const float sw3  = ws[13];

  // stage + fake-quantize weights into LDS ([k][j] layout, float4 j-reads).
  // One-time cost: IEEE div keeps this bit-exact vs reference.
  for (int i = tid; i < G4; i += NTHR) {
    s_wih[i] = fminf(fmaxf(rintf(w_ih[i]/swih), -127.f), 127.f)*swih;
    s_b[i]   = bias[i];
  }
  for (int i = tid; i < HIDN*G4; i += NTHR) {
    int j = i/HIDN, k = i - j*HIDN;           // src w_hh[j][k]
    s_whh[k*G4+j] = fminf(fmaxf(rintf(w_hh[i]/swhh), -127.f), 127.f)*swhh;
  }
  for (int i = tid; i < 64*HIDN; i += NTHR) {
    int j = i/HIDN, k = i - j*HIDN;           // src W1[j][k]
    s_W1[k*64+j] = fminf(fmaxf(rintf(W1[i]/sw1), -127.f), 127.f)*sw1;
  }
  for (int i = tid; i < 32*64; i += NTHR) {
    int j = i>>6, k = i&63;                   // src W2[j][k]
    s_W2[k*32+j] = fminf(fmaxf(rintf(W2[i]/sw2), -127.f), 127.f)*sw2;
  }
  for (int i = tid; i < 4*32; i += NTHR) {
    int j = i>>5, k = i&31;                   // src W3[j][k]
    s_W3[k*4+j] = fminf(fmaxf(rintf(W3[i]/sw3), -127.f), 127.f)*sw3;
  }
  if (tid < 64) s_b1v[tid] = b1[tid];
  if (tid < 32) s_b2v[tid] = b2[tid];
  if (tid < 4)  s_b3v[tid] = b3[tid];
  __syncthreads();

  const long bI = (long)blk*NTHR + tid;
  const float* xrow = x + bI*SEQL;
  const float inv_sx = __builtin_amdgcn_rcpf(sx);

  float h[HIDN], c[HIDN];
  #pragma unroll
  for (int k=0;k<HIDN;++k){ h[k]=0.f; c[k]=0.f; }

  float4 x4v;
  #pragma unroll 1
  for (int t=0; t<SEQL; ++t) {
    if ((t&3)==0) x4v = *(const float4*)(xrow + t);
    float xv = (t&3)==1 ? x4v.y : ((t&3)==2 ? x4v.z : ((t&3)==3 ? x4v.w : x4v.x));
    float xq = __fmul_rn(fminf(fmaxf(qround(xv, sx, inv_sx, 1e-4f), -127.f), 127.f), sx);

    // hw = h @ w_hh^T, k-ordered fma from 0 (canonical dot order)
    float hw[G4];
    #pragma unroll
    for (int j=0;j<G4;++j) hw[j]=0.f;
    #pragma unroll
    for (int k=0;k<HIDN;++k) {
      float hk = h[k];
      #pragma unroll
      for (int j=0;j<G4;j+=4) {
        float4 w = *(const float4*)&s_whh[k*G4+j];
        hw[j]   = fmaf(hk, w.x, hw[j]);
        hw[j+1] = fmaf(hk, w.y, hw[j+1]);
        hw[j+2] = fmaf(hk, w.z, hw[j+2]);
        hw[j+3] = fmaf(hk, w.w, hw[j+3]);
      }
    }
    // gates = (x@wihT + hw) + b, left-assoc, no contraction
    float lm = 0.f;
    #pragma unroll
    for (int j=0;j<G4;++j) {
      float g = __fadd_rn(__fadd_rn(__fmul_rn(xq, s_wih[j]), hw[j]), s_b[j]);
      hw[j] = g;
      lm = fmaxf(lm, fabsf(g));
    }
    float gm = phase_max(lm, 2*t, slots, blk, tid, s_red, &s_bc);
    float s1 = fmaxf(gm, 1e-8f)/31.0f;        // gate_acc scale (uniform)
    float inv1 = __builtin_amdgcn_rcpf(s1);

    // Build activation LUTs for the 63 possible quantized-gate values.
    // Entry n: exact same instruction sequence as the per-thread path on
    // input RN(n*s1) -> bit-identical results.
    if (tid < 63) {
      float q  = __fmul_rn((float)(tid-31), s1);
      float ti = tanh_xla(0.5f*q);
      int ni = (int)rintf(fmaf(0.5f, ti, 0.5f)*63.0f);
      ni = min(max(ni,0),63);
      s_lutsig[tid] = (float)ni/63.0f;
    } else if (tid >= 64 && tid < 127) {
      int n = tid - 64 - 31;
      float q  = __fmul_rn((float)n, s1);
      float tg = tanh_xla(q);
      int ng = (int)rintf(tg*31.0f);
      ng = min(max(ng,-31),31);
      s_luttg[tid-64] = (float)ng/31.0f;
    }
    __syncthreads();

    float og[HIDN];
    float lm2 = 0.f;
    #pragma unroll
    for (int k=0;k<HIDN;++k) {
      int ii = min(max((int)qround(hw[k   ], s1, inv1, 2e-5f),-31),31)+31;
      int fi = min(max((int)qround(hw[20+k], s1, inv1, 2e-5f),-31),31)+31;
      int gi = min(max((int)qround(hw[40+k], s1, inv1, 2e-5f),-31),31)+31;
      int oi = min(max((int)qround(hw[60+k], s1, inv1, 2e-5f),-31),31)+31;
      float iv = s_lutsig[ii];
      float fv = s_lutsig[fi];
      float gv = s_luttg[gi];
      og[k]    = s_lutsig[oi];
      // c_new = (f*c) + (i*g), unfused
      float pc = __fadd_rn(__fmul_rn(fv, c[k]), __fmul_rn(iv, gv));
      c[k] = pc;
      lm2 = fmaxf(lm2, fabsf(pc));
    }
    float gm2 = phase_max(lm2, 2*t+1, slots, blk, tid, s_red, &s_bc);
    float s2 = fmaxf(gm2, 1e-8f)/31.0f;       // cell_state scale (uniform)
    float inv2 = __builtin_amdgcn_rcpf(s2);
    if (tid < 63) {
      float q  = __fmul_rn((float)(tid-31), s2);
      float tc = tanh_xla(q);
      int nc = (int)rintf(tc*31.0f);
      nc = min(max(nc,-31),31);
      s_luttc[tid] = (float)nc/31.0f;
    }
    __syncthreads();
    #pragma unroll
    for (int k=0;k<HIDN;++k) {
      int m = min(max((int)qround(c[k], s2, inv2, 2e-5f),-31),31);
      float cn = __fmul_rn((float)m, s2);
      c[k] = cn;
      h[k] = __fmul_rn(og[k], s_luttc[m+31]);
    }
  }

  // ---- MLP head ----
  float lm3 = 0.f;
  float a0[HIDN];
  #pragma unroll
  for (int k=0;k<HIDN;++k){ float r = fmaxf(h[k],0.f); a0[k]=r; lm3=fmaxf(lm3,r); }
  float gm3 = phase_max(lm3, 128, slots, blk, tid, s_red, &s_bc);
  float s3 = fmaxf(gm3,1e-8f)/63.0f;          // unsigned 6b
  float inv3 = __builtin_amdgcn_rcpf(s3);
  #pragma unroll
  for (int k=0;k<HIDN;++k)
    a0[k] = __fmul_rn(fminf(fmaxf(qround(a0[k], s3, inv3, 4e-5f),0.f),63.f), s3);

  float o1[64];
  #pragma unroll
  for (int j=0;j<64;++j) o1[j] = 0.f;
  #pragma unroll
  for (int k=0;k<HIDN;++k) {
    float ak = a0[k];
    #pragma unroll
    for (int j=0;j<64;j+=4) {
      float4 w = *(const float4*)&s_W1[k*64+j];
      o1[j]   = fmaf(ak,w.x,o1[j]);
      o1[j+1] = fmaf(ak,w.y,o1[j+1]);
      o1[j+2] = fmaf(ak,w.z,o1[j+2]);
      o1[j+3] = fmaf(ak,w.w,o1[j+3]);
    }
  }
  float lm4 = 0.f;
  #pragma unroll
  for (int j=0;j<64;++j){ o1[j]=fmaxf(__fadd_rn(o1[j],s_b1v[j]),0.f); lm4=fmaxf(lm4,o1[j]); }
  float gm4 = phase_max(lm4, 129, slots, blk, tid, s_red, &s_bc);
  float s4 = fmaxf(gm4,1e-8f)/63.0f;
  float inv4 = __builtin_amdgcn_rcpf(s4);
  #pragma unroll
  for (int j=0;j<64;++j)
    o1[j] = __fmul_rn(fminf(fmaxf(qround(o1[j], s4, inv4, 4e-5f),0.f),63.f), s4);

  float o2[32];
  #pragma unroll
  for (int j=0;j<32;++j) o2[j] = 0.f;
  #pragma unroll
  for (int k=0;k<64;++k) {
    float ak = o1[k];
    #pragma unroll
    for (int j=0;j<32;j+=4) {
      float4 w = *(const float4*)&s_W2[k*32+j];
      o2[j]   = fmaf(ak,w.x,o2[j]);
      o2[j+1] = fmaf(ak,w.y,o2[j+1]);
      o2[j+2] = fmaf(ak,w.z,o2[j+2]);
      o2[j+3] = fmaf(ak,w.w,o2[j+3]);
    }
  }
  float lm5=0.f;
  #pragma unroll
  for (int j=0;j<32;++j){ o2[j]=fmaxf(__fadd_rn(o2[j],s_b2v[j]),0.f); lm5=fmaxf(lm5,o2[j]); }
  float gm5 = phase_max(lm5, 130, slots, blk, tid, s_red, &s_bc);
  float s5 = fmaxf(gm5,1e-8f)/63.0f;
  float inv5 = __builtin_amdgcn_rcpf(s5);
  #pragma unroll
  for (int j=0;j<32;++j)
    o2[j] = __fmul_rn(fminf(fmaxf(qround(o2[j], s5, inv5, 4e-5f),0.f),63.f), s5);

  float o3[4] = {0.f,0.f,0.f,0.f};
  #pragma unroll
  for (int k=0;k<32;++k) {
    float ak = o2[k];
    float4 w = *(const float4*)&s_W3[k*4];
    o3[0]=fmaf(ak,w.x,o3[0]); o3[1]=fmaf(ak,w.y,o3[1]);
    o3[2]=fmaf(ak,w.z,o3[2]); o3[3]=fmaf(ak,w.w,o3[3]);
  }
  float4 res;
  res.x = fmaxf(__fadd_rn(o3[0],s_b3v[0]),0.f);
  res.y = fmaxf(__fadd_rn(o3[1],s_b3v[1]),0.f);
  res.z = fmaxf(__fadd_rn(o3[2],s_b3v[2]),0.f);
  res.w = fmaxf(__fadd_rn(o3[3],s_b3v[3]),0.f);
  ((float4*)out)[bI] = res;
}

extern "C" void kernel_launch(void* const* d_in, const int* in_sizes, int n_in,
                              void* d_out, int out_size, void* d_ws, size_t ws_size,
                              hipStream_t stream) {
  const float* x    = (const float*)d_in[0];
  const float* w_ih = (const float*)d_in[1];
  const float* w_hh = (const float*)d_in[2];
  const float* b    = (const float*)d_in[3];
  const float* W1   = (const float*)d_in[4];
  const float* b1   = (const float*)d_in[5];
  const float* W2   = (const float*)d_in[6];
  const float* b2   = (const float*)d_in[7];
  const float* W3   = (const float*)d_in[8];
  const float* b3   = (const float*)d_in[9];
  float* out = (float*)d_out;
  float* ws  = (float*)d_ws;

  int n4 = in_sizes[0]/4;
  kinit<<<1,256,0,stream>>>(ws);
  kmaxabs_x<<<1024,256,0,stream>>>((const float4*)x, n4, (int*)ws);
  kscales<<<1,320,0,stream>>>(w_ih,w_hh,W1,W2,W3,ws);
  // Plain launch (NOT cooperative: not graph-capturable). Co-residency is
  // structural: 256 blocks, 1 block/CU x 256 CUs at __launch_bounds__(512,2).
  kmain<<<dim3(NBLK), dim3(NTHR), 0, stream>>>(x,w_ih,w_hh,b,W1,b1,W2,b2,W3,b3,out,ws);
}